// Round 15
// baseline (300.986 us; speedup 1.0000x reference)
//
#include <hip/hip_runtime.h>
#include <hip/hip_bf16.h>

// ---------- bf16 helpers ----------
__device__ __forceinline__ float bf2f(unsigned short u) {
    return __uint_as_float(((unsigned int)u) << 16);
}
__device__ __forceinline__ unsigned short f2bf(float f) {
    unsigned int u = __float_as_uint(f);
    return (unsigned short)((u + 0x7FFFu + ((u >> 16) & 1u)) >> 16);
}

// ---------- inline int64 edge_index detection ----------
__device__ __forceinline__ bool is_i64(const int* __restrict__ e) {
    int z = 0;
#pragma unroll
    for (int i = 0; i < 16; ++i) z |= e[2 * i + 1];
    return z == 0;
}

// ---------- FUSED: gemm1 (blocks < gemmBlocks) + hist_rank (rest) ----------
template <int OUT_DIM, int GST>
__global__ __launch_bounds__(256) void gemm1_hist_fused(
        const float* __restrict__ in, const float* __restrict__ Wl,
        const float* __restrict__ Wr, const float* __restrict__ bias,
        unsigned short* __restrict__ gout, float* __restrict__ sout,
        int n_nodes, int gemmBlocks,
        const int* __restrict__ eidx, int n_edges,
        int* __restrict__ deg, int* __restrict__ rank) {
    __shared__ unsigned int sWp[64][65];
    __shared__ float sB[OUT_DIM];
    __shared__ float sX[4][8][68];

    if ((int)blockIdx.x >= gemmBlocks) {
        const int half = (n_edges + 1) / 2;
        const int e = (blockIdx.x - gemmBlocks) * blockDim.x + threadIdx.x;
        if (e >= half) return;
        const bool i64 = is_i64(eidx);
        {
            int d = i64 ? eidx[2 * (n_edges + e)] : eidx[n_edges + e];
            rank[e] = atomicAdd(&deg[d], 1);
        }
        const int e2 = e + half;
        if (e2 < n_edges) {
            int d = i64 ? eidx[2 * (n_edges + e2)] : eidx[n_edges + e2];
            rank[e2] = atomicAdd(&deg[d], 1);
        }
        return;
    }

    for (int idx = threadIdx.x; idx < OUT_DIM * 64; idx += 256) {
        const int r = idx >> 6, c = idx & 63;
        sWp[c][r] = (unsigned int)f2bf(Wl[idx]) | ((unsigned int)f2bf(Wr[idx]) << 16);
    }
    if (threadIdx.x < OUT_DIM) sB[threadIdx.x] = bias[threadIdx.x];
    __syncthreads();

    const int g = threadIdx.x >> 6;
    const int j = threadIdx.x & 63;
    const bool jv = (j < OUT_DIM);
    const int jj = jv ? j : 0;
    const int blockBase = blockIdx.x * 128;

#pragma unroll 1
    for (int it = 0; it < 4; ++it) {
        const int nb = blockBase + it * 32 + g * 8;
        if (nb >= n_nodes) break;
#pragma unroll
        for (int n = 0; n < 8; ++n) {
            const int node = nb + n;
            sX[g][n][j] = (node < n_nodes) ? in[(size_t)node * 64 + j] : 0.0f;
        }
        float al[8], ar[8];
#pragma unroll
        for (int n = 0; n < 8; ++n) { al[n] = 0.0f; ar[n] = 0.0f; }

#pragma unroll 2
        for (int q = 0; q < 16; ++q) {
            const unsigned int w0 = sWp[4 * q + 0][jj];
            const unsigned int w1 = sWp[4 * q + 1][jj];
            const unsigned int w2 = sWp[4 * q + 2][jj];
            const unsigned int w3 = sWp[4 * q + 3][jj];
            const float4 x0 = *(const float4*)&sX[g][0][4 * q];
            const float4 x1 = *(const float4*)&sX[g][1][4 * q];
            const float4 x2 = *(const float4*)&sX[g][2][4 * q];
            const float4 x3 = *(const float4*)&sX[g][3][4 * q];
            const float4 x4 = *(const float4*)&sX[g][4][4 * q];
            const float4 x5 = *(const float4*)&sX[g][5][4 * q];
            const float4 x6 = *(const float4*)&sX[g][6][4 * q];
            const float4 x7 = *(const float4*)&sX[g][7][4 * q];
#define DG_STEP(WP, M)                                                         \
            {                                                                  \
                const float wl_ = __uint_as_float((WP) << 16);                 \
                const float wr_ = __uint_as_float((WP) & 0xFFFF0000u);         \
                al[0] = fmaf(x0.M, wl_, al[0]); ar[0] = fmaf(x0.M, wr_, ar[0]);\
                al[1] = fmaf(x1.M, wl_, al[1]); ar[1] = fmaf(x1.M, wr_, ar[1]);\
                al[2] = fmaf(x2.M, wl_, al[2]); ar[2] = fmaf(x2.M, wr_, ar[2]);\
                al[3] = fmaf(x3.M, wl_, al[3]); ar[3] = fmaf(x3.M, wr_, ar[3]);\
                al[4] = fmaf(x4.M, wl_, al[4]); ar[4] = fmaf(x4.M, wr_, ar[4]);\
                al[5] = fmaf(x5.M, wl_, al[5]); ar[5] = fmaf(x5.M, wr_, ar[5]);\
                al[6] = fmaf(x6.M, wl_, al[6]); ar[6] = fmaf(x6.M, wr_, ar[6]);\
                al[7] = fmaf(x7.M, wl_, al[7]); ar[7] = fmaf(x7.M, wr_, ar[7]);\
            }
            DG_STEP(w0, x)
            DG_STEP(w1, y)
            DG_STEP(w2, z)
            DG_STEP(w3, w)
#undef DG_STEP
        }

        const float bb = jv ? sB[jj] : 0.0f;
#pragma unroll
        for (int n = 0; n < 8; ++n) {
            const int node = nb + n;
            if (node < n_nodes) {
                if (jv) {
                    gout[(size_t)node * GST + j] = f2bf(al[n]);
                    sout[(size_t)node * OUT_DIM + j] = ar[n] + bb;
                } else if (j < GST) {
                    gout[(size_t)node * GST + j] = 0;
                }
            }
        }
    }
}

// ---------- FUSED: gather1 + gemm2 (h never touches global memory) ----------
// Per wave: gather-mean 8 nodes from g1/s1 (+relu) -> rows land in the
// wave-private sX slot (lanes 0-15 hold the 64-wide row as float4s, exactly
// dual_gemm3's staging layout) -> run the proven dense loop -> write g2/s2.
// No barrier after weight staging needed within iterations (wave-private LDS).
template <int OUT_DIM, int GST>
__global__ __launch_bounds__(256) void gather_gemm_fused(
        const unsigned short* __restrict__ gsrc,  // g1 [N,64] bf16
        const float* __restrict__ sadd,           // s1 [N,64] f32
        const int* __restrict__ off, const int* __restrict__ csr,
        const float* __restrict__ Wl, const float* __restrict__ Wr,
        const float* __restrict__ bias,
        unsigned short* __restrict__ gout,        // g2 [N,GST] bf16
        float* __restrict__ sout,                 // s2 [N,OUT_DIM] f32
        int n_nodes) {
    __shared__ unsigned int sWp[64][65];
    __shared__ float sB[OUT_DIM];
    __shared__ float sX[4][8][68];

    for (int idx = threadIdx.x; idx < OUT_DIM * 64; idx += 256) {
        const int r = idx >> 6, c = idx & 63;
        sWp[c][r] = (unsigned int)f2bf(Wl[idx]) | ((unsigned int)f2bf(Wr[idx]) << 16);
    }
    if (threadIdx.x < OUT_DIM) sB[threadIdx.x] = bias[threadIdx.x];
    __syncthreads();

    const int g = threadIdx.x >> 6;
    const int j = threadIdx.x & 63;
    const int c = j & 15, r4 = j >> 4;     // gather: col-group, row-group
    const bool jv = (j < OUT_DIM);
    const int jj = jv ? j : 0;
    const int blockBase = blockIdx.x * 64; // 64 nodes per block (2 x 32)

#pragma unroll 1
    for (int it = 0; it < 2; ++it) {
        const int nb = blockBase + it * 32 + g * 8;
        if (nb >= n_nodes) break;

        // ---- gather phase: 8 nodes -> sX (wave-private, no barrier) ----
#pragma unroll 1
        for (int n = 0; n < 8; ++n) {
            const int node = nb + n;
            if (node >= n_nodes) {
                if (j < 16) {
                    float4 z = {0.f, 0.f, 0.f, 0.f};
                    *(float4*)&sX[g][n][4 * j] = z;
                }
                continue;
            }
            const int e0 = off[node], e1 = off[node + 1];
            float4 a0 = {0.f,0.f,0.f,0.f}, a1 = a0, a2 = a0, a3 = a0;
            for (int i = e0; i < e1; i += 16) {
                const int i0 = i + r4, i1 = i0 + 4, i2 = i0 + 8, i3 = i0 + 12;
                if (i0 < e1) {
                    const int s = csr[i0];
                    const ushort4 u = *(const ushort4*)(gsrc + (size_t)s * 64 + 4 * c);
                    a0.x += bf2f(u.x); a0.y += bf2f(u.y); a0.z += bf2f(u.z); a0.w += bf2f(u.w);
                }
                if (i1 < e1) {
                    const int s = csr[i1];
                    const ushort4 u = *(const ushort4*)(gsrc + (size_t)s * 64 + 4 * c);
                    a1.x += bf2f(u.x); a1.y += bf2f(u.y); a1.z += bf2f(u.z); a1.w += bf2f(u.w);
                }
                if (i2 < e1) {
                    const int s = csr[i2];
                    const ushort4 u = *(const ushort4*)(gsrc + (size_t)s * 64 + 4 * c);
                    a2.x += bf2f(u.x); a2.y += bf2f(u.y); a2.z += bf2f(u.z); a2.w += bf2f(u.w);
                }
                if (i3 < e1) {
                    const int s = csr[i3];
                    const ushort4 u = *(const ushort4*)(gsrc + (size_t)s * 64 + 4 * c);
                    a3.x += bf2f(u.x); a3.y += bf2f(u.y); a3.z += bf2f(u.z); a3.w += bf2f(u.w);
                }
            }
            float4 a;
            a.x = (a0.x + a1.x) + (a2.x + a3.x);
            a.y = (a0.y + a1.y) + (a2.y + a3.y);
            a.z = (a0.z + a1.z) + (a2.z + a3.z);
            a.w = (a0.w + a1.w) + (a2.w + a3.w);
            a.x += __shfl_xor(a.x, 16); a.y += __shfl_xor(a.y, 16);
            a.z += __shfl_xor(a.z, 16); a.w += __shfl_xor(a.w, 16);
            a.x += __shfl_xor(a.x, 32); a.y += __shfl_xor(a.y, 32);
            a.z += __shfl_xor(a.z, 32); a.w += __shfl_xor(a.w, 32);
            const int deg = e1 - e0;
            const float inv = (deg > 0) ? 1.0f / (float)deg : 0.0f;
            if (j < 16) {
                const float4 sv = *(const float4*)(sadd + (size_t)node * 64 + 4 * j);
                float4 o;
                o.x = fmaxf(fmaf(a.x, inv, sv.x), 0.f);   // relu(h)
                o.y = fmaxf(fmaf(a.y, inv, sv.y), 0.f);
                o.z = fmaxf(fmaf(a.z, inv, sv.z), 0.f);
                o.w = fmaxf(fmaf(a.w, inv, sv.w), 0.f);
                *(float4*)&sX[g][n][4 * j] = o;
            }
        }

        // ---- dense phase (identical to proven dual_gemm3 inner loop) ----
        float al[8], ar[8];
#pragma unroll
        for (int n = 0; n < 8; ++n) { al[n] = 0.0f; ar[n] = 0.0f; }

#pragma unroll 2
        for (int q = 0; q < 16; ++q) {
            const unsigned int w0 = sWp[4 * q + 0][jj];
            const unsigned int w1 = sWp[4 * q + 1][jj];
            const unsigned int w2 = sWp[4 * q + 2][jj];
            const unsigned int w3 = sWp[4 * q + 3][jj];
            const float4 x0 = *(const float4*)&sX[g][0][4 * q];
            const float4 x1 = *(const float4*)&sX[g][1][4 * q];
            const float4 x2 = *(const float4*)&sX[g][2][4 * q];
            const float4 x3 = *(const float4*)&sX[g][3][4 * q];
            const float4 x4 = *(const float4*)&sX[g][4][4 * q];
            const float4 x5 = *(const float4*)&sX[g][5][4 * q];
            const float4 x6 = *(const float4*)&sX[g][6][4 * q];
            const float4 x7 = *(const float4*)&sX[g][7][4 * q];
#define DG_STEP(WP, M)                                                         \
            {                                                                  \
                const float wl_ = __uint_as_float((WP) << 16);                 \
                const float wr_ = __uint_as_float((WP) & 0xFFFF0000u);         \
                al[0] = fmaf(x0.M, wl_, al[0]); ar[0] = fmaf(x0.M, wr_, ar[0]);\
                al[1] = fmaf(x1.M, wl_, al[1]); ar[1] = fmaf(x1.M, wr_, ar[1]);\
                al[2] = fmaf(x2.M, wl_, al[2]); ar[2] = fmaf(x2.M, wr_, ar[2]);\
                al[3] = fmaf(x3.M, wl_, al[3]); ar[3] = fmaf(x3.M, wr_, ar[3]);\
                al[4] = fmaf(x4.M, wl_, al[4]); ar[4] = fmaf(x4.M, wr_, ar[4]);\
                al[5] = fmaf(x5.M, wl_, al[5]); ar[5] = fmaf(x5.M, wr_, ar[5]);\
                al[6] = fmaf(x6.M, wl_, al[6]); ar[6] = fmaf(x6.M, wr_, ar[6]);\
                al[7] = fmaf(x7.M, wl_, al[7]); ar[7] = fmaf(x7.M, wr_, ar[7]);\
            }
            DG_STEP(w0, x)
            DG_STEP(w1, y)
            DG_STEP(w2, z)
            DG_STEP(w3, w)
#undef DG_STEP
        }

        const float bb = jv ? sB[jj] : 0.0f;
#pragma unroll
        for (int n = 0; n < 8; ++n) {
            const int node = nb + n;
            if (node < n_nodes) {
                if (jv) {
                    gout[(size_t)node * GST + j] = f2bf(al[n]);
                    sout[(size_t)node * OUT_DIM + j] = ar[n] + bb;
                } else if (j < GST) {
                    gout[(size_t)node * GST + j] = 0;
                }
            }
        }
    }
}

// ---------- standalone hist + rank (tierC/D path) ----------
__global__ void hist_rank_kernel(const int* __restrict__ eidx, int n_edges,
                                 int* __restrict__ deg, int* __restrict__ rank) {
    const int half = (n_edges + 1) / 2;
    const int e = blockIdx.x * blockDim.x + threadIdx.x;
    if (e >= half) return;
    const bool i64 = is_i64(eidx);
    {
        int d = i64 ? eidx[2 * (n_edges + e)] : eidx[n_edges + e];
        rank[e] = atomicAdd(&deg[d], 1);
    }
    const int e2 = e + half;
    if (e2 < n_edges) {
        int d = i64 ? eidx[2 * (n_edges + e2)] : eidx[n_edges + e2];
        rank[e2] = atomicAdd(&deg[d], 1);
    }
}

// ---------- atomic-free fill ----------
__global__ void fill_rank_kernel(const int* __restrict__ eidx, int n_edges,
                                 const int* __restrict__ off, const int* __restrict__ rank,
                                 int* __restrict__ csr) {
    const int half = (n_edges + 1) / 2;
    const int e = blockIdx.x * blockDim.x + threadIdx.x;
    if (e >= half) return;
    const bool i64 = is_i64(eidx);
    {
        int s, d;
        if (i64) { s = eidx[2 * e]; d = eidx[2 * (n_edges + e)]; }
        else     { s = eidx[e];     d = eidx[n_edges + e]; }
        __builtin_nontemporal_store(s, &csr[off[d] + rank[e]]);
    }
    const int e2 = e + half;
    if (e2 < n_edges) {
        int s, d;
        if (i64) { s = eidx[2 * e2]; d = eidx[2 * (n_edges + e2)]; }
        else     { s = eidx[e2];     d = eidx[n_edges + e2]; }
        __builtin_nontemporal_store(s, &csr[off[d] + rank[e2]]);
    }
}

// ---------- legacy atomic fill (tierC/D) ----------
__global__ void fill_kernel(const int* __restrict__ eidx, int n_edges,
                            int* __restrict__ cursor, int* __restrict__ csr) {
    int e = blockIdx.x * blockDim.x + threadIdx.x;
    if (e >= n_edges) return;
    const bool i64 = is_i64(eidx);
    int s, d;
    if (i64) { s = eidx[2 * e]; d = eidx[2 * (n_edges + e)]; }
    else     { s = eidx[e];     d = eidx[n_edges + e]; }
    int pos = atomicAdd(&cursor[d], 1);
    csr[pos] = s;
}

// ---------- 3-phase parallel exclusive scan ----------
#define TILE 1024
__global__ void scan_p1(const int* __restrict__ deg, int* __restrict__ bsum, int n) {
    __shared__ int red[256];
    const int t = threadIdx.x;
    const int base = blockIdx.x * TILE + t * 4;
    int s = 0;
#pragma unroll
    for (int k = 0; k < 4; ++k) { int i = base + k; if (i < n) s += deg[i]; }
    red[t] = s;
    __syncthreads();
    for (int d = 128; d > 0; d >>= 1) {
        if (t < d) red[t] += red[t + d];
        __syncthreads();
    }
    if (t == 0) bsum[blockIdx.x] = red[0];
}

__global__ void scan_p2(int* __restrict__ bsum, int* __restrict__ off, int nb, int n) {
    __shared__ int s[1024];
    const int t = threadIdx.x;
    s[t] = (t < nb) ? bsum[t] : 0;
    __syncthreads();
    for (int d = 1; d < 1024; d <<= 1) {
        int v = (t >= d) ? s[t - d] : 0;
        __syncthreads();
        s[t] += v;
        __syncthreads();
    }
    if (t < nb) bsum[t] = (t == 0) ? 0 : s[t - 1];
    if (t == 0) off[n] = s[nb - 1];
}

__global__ void scan_p3(const int* __restrict__ deg, const int* __restrict__ bsum,
                        int* __restrict__ off, int* __restrict__ cursor, int n) {
    __shared__ int red[256];
    const int t = threadIdx.x;
    const int base = blockIdx.x * TILE + t * 4;
    int v0 = 0, v1 = 0, v2 = 0, v3 = 0;
    if (base + 0 < n) v0 = deg[base + 0];
    if (base + 1 < n) v1 = deg[base + 1];
    if (base + 2 < n) v2 = deg[base + 2];
    if (base + 3 < n) v3 = deg[base + 3];
    const int mysum = v0 + v1 + v2 + v3;
    red[t] = mysum;
    __syncthreads();
    for (int d = 1; d < 256; d <<= 1) {
        int u = (t >= d) ? red[t - d] : 0;
        __syncthreads();
        red[t] += u;
        __syncthreads();
    }
    int run = bsum[blockIdx.x] + red[t] - mysum;
    if (base + 0 < n) { off[base + 0] = run; cursor[base + 0] = run; run += v0; }
    if (base + 1 < n) { off[base + 1] = run; cursor[base + 1] = run; run += v1; }
    if (base + 2 < n) { off[base + 2] = run; cursor[base + 2] = run; run += v2; }
    if (base + 3 < n) { off[base + 3] = run; cursor[base + 3] = run; run += v3; }
}

// ---------- pure bf16 gather: out = [relu]( gather_mean(gsrc) + sadd ) ----------
template <int SRC_STRIDE, int CGROUPS, int OUT_DIM, bool RELU>
__global__ __launch_bounds__(256) void gather_addmul_bf16(
        const unsigned short* __restrict__ gsrc,
        const float* __restrict__ sadd,
        const int* __restrict__ off, const int* __restrict__ csr,
        float* __restrict__ out, int n_nodes) {
    const int l = threadIdx.x & 63;
    const int wave = (int)((blockIdx.x * blockDim.x + threadIdx.x) >> 6);
    const int c = l & 15, r = l >> 4;
    const bool cact = (c < CGROUPS);
    const int n0 = wave * 8;

    for (int n = n0; n < n0 + 8; ++n) {
        if (n >= n_nodes) return;
        const int e0 = off[n], e1 = off[n + 1];
        float4 a0 = {0.f,0.f,0.f,0.f}, a1 = a0, a2 = a0, a3 = a0;
        for (int i = e0; i < e1; i += 16) {
            const int i0 = i + r, i1 = i0 + 4, i2 = i0 + 8, i3 = i0 + 12;
            if (cact && i0 < e1) {
                const int s = csr[i0];
                const ushort4 u = *(const ushort4*)(gsrc + (size_t)s * SRC_STRIDE + 4 * c);
                a0.x += bf2f(u.x); a0.y += bf2f(u.y); a0.z += bf2f(u.z); a0.w += bf2f(u.w);
            }
            if (cact && i1 < e1) {
                const int s = csr[i1];
                const ushort4 u = *(const ushort4*)(gsrc + (size_t)s * SRC_STRIDE + 4 * c);
                a1.x += bf2f(u.x); a1.y += bf2f(u.y); a1.z += bf2f(u.z); a1.w += bf2f(u.w);
            }
            if (cact && i2 < e1) {
                const int s = csr[i2];
                const ushort4 u = *(const ushort4*)(gsrc + (size_t)s * SRC_STRIDE + 4 * c);
                a2.x += bf2f(u.x); a2.y += bf2f(u.y); a2.z += bf2f(u.z); a2.w += bf2f(u.w);
            }
            if (cact && i3 < e1) {
                const int s = csr[i3];
                const ushort4 u = *(const ushort4*)(gsrc + (size_t)s * SRC_STRIDE + 4 * c);
                a3.x += bf2f(u.x); a3.y += bf2f(u.y); a3.z += bf2f(u.z); a3.w += bf2f(u.w);
            }
        }
        float4 a;
        a.x = (a0.x + a1.x) + (a2.x + a3.x);
        a.y = (a0.y + a1.y) + (a2.y + a3.y);
        a.z = (a0.z + a1.z) + (a2.z + a3.z);
        a.w = (a0.w + a1.w) + (a2.w + a3.w);
        a.x += __shfl_xor(a.x, 16); a.y += __shfl_xor(a.y, 16);
        a.z += __shfl_xor(a.z, 16); a.w += __shfl_xor(a.w, 16);
        a.x += __shfl_xor(a.x, 32); a.y += __shfl_xor(a.y, 32);
        a.z += __shfl_xor(a.z, 32); a.w += __shfl_xor(a.w, 32);
        const int deg = e1 - e0;
        const float inv = (deg > 0) ? 1.0f / (float)deg : 0.0f;
        if (4 * l < OUT_DIM) {
            const float4 sv = *(const float4*)(sadd + (size_t)n * OUT_DIM + 4 * l);
            float4 o;
            o.x = fmaf(a.x, inv, sv.x);
            o.y = fmaf(a.y, inv, sv.y);
            o.z = fmaf(a.z, inv, sv.z);
            o.w = fmaf(a.w, inv, sv.w);
            if (RELU) {
                o.x = fmaxf(o.x, 0.f); o.y = fmaxf(o.y, 0.f);
                o.z = fmaxf(o.z, 0.f); o.w = fmaxf(o.w, 0.f);
            }
            *(float4*)(out + (size_t)n * OUT_DIM + 4 * l) = o;
        }
    }
}

// ---------- tierC: fused layer, f4 gather + in-kernel dense (f32 only) ----------
#define NPB 32
template <int OUT_DIM, bool RELU>
__global__ __launch_bounds__(512, 8) void fused_layer_f4(
        const float* __restrict__ feat,
        const int* __restrict__ off, const int* __restrict__ csr,
        const float* __restrict__ Wl, const float* __restrict__ Wr,
        const float* __restrict__ bias,
        float* __restrict__ out, int n_nodes) {
    __shared__ float sWl[OUT_DIM][65];
    __shared__ float sWr[OUT_DIM][65];
    __shared__ float sB[OUT_DIM];
    __shared__ float sA[8][64];
    __shared__ float sX[8][64];

    for (int idx = threadIdx.x; idx < OUT_DIM * 64; idx += 512) {
        sWl[idx >> 6][idx & 63] = Wl[idx];
        sWr[idx >> 6][idx & 63] = Wr[idx];
    }
    if (threadIdx.x < OUT_DIM) sB[threadIdx.x] = bias[threadIdx.x];
    __syncthreads();

    const int g = threadIdx.x >> 6;
    const int l = threadIdx.x & 63;
    const int c = l & 15, r = l >> 4;
    const int base = blockIdx.x * NPB;

#pragma unroll 1
    for (int it = 0; it < NPB / 8; ++it) {
        const int node = base + it * 8 + g;
        if (node >= n_nodes) break;
        const int e0 = off[node], e1 = off[node + 1];
        const float selfv = feat[(size_t)node * 64 + l];
        float4 a0 = {0.f,0.f,0.f,0.f}, a1 = a0, a2 = a0, a3 = a0;
        for (int i = e0; i < e1; i += 16) {
            const int i0 = i + r, i1 = i0 + 4, i2 = i0 + 8, i3 = i0 + 12;
            if (i0 < e1) { const int s = csr[i0];
                const float4 v = *(const float4*)(feat + (size_t)s * 64 + 4 * c);
                a0.x += v.x; a0.y += v.y; a0.z += v.z; a0.w += v.w; }
            if (i1 < e1) { const int s = csr[i1];
                const float4 v = *(const float4*)(feat + (size_t)s * 64 + 4 * c);
                a1.x += v.x; a1.y += v.y; a1.z += v.z; a1.w += v.w; }
            if (i2 < e1) { const int s = csr[i2];
                const float4 v = *(const float4*)(feat + (size_t)s * 64 + 4 * c);
                a2.x += v.x; a2.y += v.y; a2.z += v.z; a2.w += v.w; }
            if (i3 < e1) { const int s = csr[i3];
                const float4 v = *(const float4*)(feat + (size_t)s * 64 + 4 * c);
                a3.x += v.x; a3.y += v.y; a3.z += v.z; a3.w += v.w; }
        }
        float4 a;
        a.x = (a0.x + a1.x) + (a2.x + a3.x);
        a.y = (a0.y + a1.y) + (a2.y + a3.y);
        a.z = (a0.z + a1.z) + (a2.z + a3.z);
        a.w = (a0.w + a1.w) + (a2.w + a3.w);
        a.x += __shfl_xor(a.x, 16); a.y += __shfl_xor(a.y, 16);
        a.z += __shfl_xor(a.z, 16); a.w += __shfl_xor(a.w, 16);
        a.x += __shfl_xor(a.x, 32); a.y += __shfl_xor(a.y, 32);
        a.z += __shfl_xor(a.z, 32); a.w += __shfl_xor(a.w, 32);
        const int deg = e1 - e0;
        const float inv = (deg > 0) ? 1.0f / (float)deg : 0.0f;
        if (l < 16) {
            float4 s4;
            s4.x = a.x * inv; s4.y = a.y * inv; s4.z = a.z * inv; s4.w = a.w * inv;
            *(float4*)&sA[g][4 * l] = s4;
        }
        sX[g][l] = selfv;
        if (l < OUT_DIM) {
            float acc = sB[l];
#pragma unroll
            for (int k = 0; k < 64; ++k) {
                acc = fmaf(sA[g][k], sWl[l][k], acc);
                acc = fmaf(sX[g][k], sWr[l][k], acc);
            }
            if (RELU) acc = fmaxf(acc, 0.0f);
            out[(size_t)node * OUT_DIM + l] = acc;
        }
    }
}

// ---------- tierD: legacy shfl-gather fused layer (bf16-capable) ----------
template <int OUT_DIM, bool RELU, bool FEAT_BF16, bool OUT_BF16>
__global__ __launch_bounds__(512, 8) void fused_layer(
        const void* __restrict__ feat,
        const int* __restrict__ off, const int* __restrict__ csr,
        const float* __restrict__ Wl, const float* __restrict__ Wr,
        const float* __restrict__ bias,
        void* __restrict__ out, int n_nodes) {
    __shared__ float sWl[OUT_DIM][65];
    __shared__ float sWr[OUT_DIM][65];
    __shared__ float sB[OUT_DIM];
    __shared__ float sA[8][64];
    __shared__ float sX[8][64];

    for (int idx = threadIdx.x; idx < OUT_DIM * 64; idx += 512) {
        sWl[idx >> 6][idx & 63] = Wl[idx];
        sWr[idx >> 6][idx & 63] = Wr[idx];
    }
    if (threadIdx.x < OUT_DIM) sB[threadIdx.x] = bias[threadIdx.x];
    __syncthreads();

    const int g = threadIdx.x >> 6;
    const int j = threadIdx.x & 63;
    const int base = blockIdx.x * NPB;

#pragma unroll 1
    for (int it = 0; it < NPB / 8; ++it) {
        const int node = base + it * 8 + g;
        if (node >= n_nodes) break;
        const int e0 = off[node], e1 = off[node + 1];
        float a0 = 0.f, a1 = 0.f, a2 = 0.f, a3 = 0.f;
        int i = e0;
        while (i < e1) {
            const int cnt = ((e1 - i) < 64) ? (e1 - i) : 64;
            const int eid = (j < cnt) ? csr[i + j] : 0;
            int t = 0;
            for (; t + 3 < cnt; t += 4) {
                const int s0 = __shfl(eid, t);
                const int s1 = __shfl(eid, t + 1);
                const int s2 = __shfl(eid, t + 2);
                const int s3 = __shfl(eid, t + 3);
                if (FEAT_BF16) {
                    a0 += bf2f(((const unsigned short*)feat)[(size_t)s0 * 64 + j]);
                    a1 += bf2f(((const unsigned short*)feat)[(size_t)s1 * 64 + j]);
                    a2 += bf2f(((const unsigned short*)feat)[(size_t)s2 * 64 + j]);
                    a3 += bf2f(((const unsigned short*)feat)[(size_t)s3 * 64 + j]);
                } else {
                    a0 += ((const float*)feat)[(size_t)s0 * 64 + j];
                    a1 += ((const float*)feat)[(size_t)s1 * 64 + j];
                    a2 += ((const float*)feat)[(size_t)s2 * 64 + j];
                    a3 += ((const float*)feat)[(size_t)s3 * 64 + j];
                }
            }
            for (; t < cnt; ++t) {
                const int s0 = __shfl(eid, t);
                a0 += FEAT_BF16 ? bf2f(((const unsigned short*)feat)[(size_t)s0 * 64 + j])
                                : ((const float*)feat)[(size_t)s0 * 64 + j];
            }
            i += cnt;
        }
        const int deg = e1 - e0;
        const float inv = (deg > 0) ? 1.0f / (float)deg : 0.0f;
        sA[g][j] = ((a0 + a1) + (a2 + a3)) * inv;
        sX[g][j] = FEAT_BF16 ? bf2f(((const unsigned short*)feat)[(size_t)node * 64 + j])
                             : ((const float*)feat)[(size_t)node * 64 + j];
        if (j < OUT_DIM) {
            float acc = sB[j];
#pragma unroll
            for (int k = 0; k < 64; ++k) {
                acc = fmaf(sA[g][k], sWl[j][k], acc);
                acc = fmaf(sX[g][k], sWr[j][k], acc);
            }
            if (RELU) acc = fmaxf(acc, 0.0f);
            if (OUT_BF16)
                ((unsigned short*)out)[(size_t)node * OUT_DIM + j] = f2bf(acc);
            else
                ((float*)out)[(size_t)node * OUT_DIM + j] = acc;
        }
    }
}

extern "C" void kernel_launch(void* const* d_in, const int* in_sizes, int n_in,
                              void* d_out, int out_size, void* d_ws, size_t ws_size,
                              hipStream_t stream) {
    const float* x   = (const float*)d_in[0];
    const int*   ei  = (const int*)d_in[1];
    const float* W1l = (const float*)d_in[2];
    const float* W1r = (const float*)d_in[3];
    const float* b1  = (const float*)d_in[4];
    const float* W2l = (const float*)d_in[5];
    const float* W2r = (const float*)d_in[6];
    const float* b2  = (const float*)d_in[7];
    float* out = (float*)d_out;

    const int n_nodes = in_sizes[0] / 64;
    const int n_edges = in_sizes[1] / 2;

    // ---- workspace layout ----
    const size_t off_b  = (size_t)(n_nodes + 1) * sizeof(int);
    const size_t cur_b  = (size_t)n_nodes * sizeof(int);
    const size_t csr_b  = (size_t)n_edges * sizeof(int);
    const size_t rank_b = (size_t)n_edges * sizeof(int);
    const size_t bsum_b = 1024 * sizeof(int);
    const size_t g1_b   = (size_t)n_nodes * 64 * sizeof(unsigned short);
    const size_t s1_b   = (size_t)n_nodes * 64 * sizeof(float);
    const size_t g2_b   = (size_t)n_nodes * 48 * sizeof(unsigned short);
    const size_t h_b    = (size_t)n_nodes * 64 * sizeof(float);
    const size_t reg1_b = g1_b + s1_b;

    char* p = (char*)d_ws;
    int* off    = (int*)p;  p += off_b;
    int* cursor = (int*)p;  p += cur_b;
    int* csr    = (int*)p;  p += csr_b;
    int* rank   = (int*)p;  p += rank_b;
    int* bsum   = (int*)p;  p += bsum_b;
    size_t used = ((size_t)(p - (char*)d_ws) + 255) / 256 * 256;
    p = (char*)d_ws + used;

    // region1: g1|s1; region2 (after): g2|s2 (g2/s2 no longer overlay g1 --
    // gather_gemm_fused reads g1/s1 while writing g2/s2, so they must be
    // disjoint. reg1 38.4 MB + g2 9.6 + s2 16 = 64 MB total.
    const size_t s2_b = (size_t)n_nodes * 40 * sizeof(float);
    const bool tierA = ws_size >= used + reg1_b + g2_b + s2_b;
    const bool tierC = ws_size >= used + h_b;

    unsigned short* g1 = (unsigned short*)p;
    float*          s1 = (float*)(p + g1_b);
    unsigned short* g2 = (unsigned short*)(p + reg1_b);
    float*          s2 = (float*)(p + reg1_b + g2_b);

    hipMemsetAsync(cursor, 0, cur_b, stream);

    const int half = (n_edges + 1) / 2;
    const int hblocks = (half + 255) / 256;
    const int gemmBlocks   = (n_nodes + 127) / 128;
    const int gatherBlocks = (n_nodes + 31) / 32;
    const int ggBlocks     = (n_nodes + 63) / 64;
    const int fusedBlocks  = (n_nodes + NPB - 1) / NPB;
    const int nb = (n_nodes + TILE - 1) / TILE;
    const int eblocks = (n_edges + 255) / 256;

    if (tierA) {
        // gemm1 and hist are independent -> one co-scheduled launch
        gemm1_hist_fused<64, 64><<<gemmBlocks + hblocks, 256, 0, stream>>>(
            x, W1l, W1r, b1, g1, s1, n_nodes, gemmBlocks,
            ei, n_edges, cursor, rank);
        scan_p1<<<nb, 256, 0, stream>>>(cursor, bsum, n_nodes);
        scan_p2<<<1, 1024, 0, stream>>>(bsum, off, nb, n_nodes);
        scan_p3<<<nb, 256, 0, stream>>>(cursor, bsum, off, cursor, n_nodes);
        fill_rank_kernel<<<hblocks, 256, 0, stream>>>(ei, n_edges, off, rank, csr);

        // gather1 + gemm2 fused: h lives only in LDS
        gather_gemm_fused<40, 48><<<ggBlocks, 256, 0, stream>>>(
            g1, s1, off, csr, W2l, W2r, b2, g2, s2, n_nodes);
        gather_addmul_bf16<48, 10, 40, false><<<gatherBlocks, 256, 0, stream>>>(
            g2, s2, off, csr, out, n_nodes);
    } else {
        hist_rank_kernel<<<hblocks, 256, 0, stream>>>(ei, n_edges, cursor, rank);
        scan_p1<<<nb, 256, 0, stream>>>(cursor, bsum, n_nodes);
        scan_p2<<<1, 1024, 0, stream>>>(bsum, off, nb, n_nodes);
        scan_p3<<<nb, 256, 0, stream>>>(cursor, bsum, off, cursor, n_nodes);
        fill_kernel<<<eblocks, 256, 0, stream>>>(ei, n_edges, cursor, csr);

        if (tierC) {
            float* hh = (float*)p;
            fused_layer_f4<64, true><<<fusedBlocks, 512, 0, stream>>>(
                x, off, csr, W1l, W1r, b1, hh, n_nodes);
            fused_layer_f4<40, false><<<fusedBlocks, 512, 0, stream>>>(
                hh, off, csr, W2l, W2r, b2, out, n_nodes);
        } else {
            void* hh = (void*)p;
            fused_layer<64, true, false, true><<<fusedBlocks, 512, 0, stream>>>(
                x, off, csr, W1l, W1r, b1, hh, n_nodes);
            fused_layer<40, false, true, false><<<fusedBlocks, 512, 0, stream>>>(
                hh, off, csr, W2l, W2r, b2, out, n_nodes);
        }
    }
}

// Round 16
// 280.673 us; speedup vs baseline: 1.0724x; 1.0724x over previous
//
#include <hip/hip_runtime.h>
#include <hip/hip_bf16.h>

// ---------- bf16 helpers ----------
__device__ __forceinline__ float bf2f(unsigned short u) {
    return __uint_as_float(((unsigned int)u) << 16);
}
__device__ __forceinline__ unsigned short f2bf(float f) {
    unsigned int u = __float_as_uint(f);
    return (unsigned short)((u + 0x7FFFu + ((u >> 16) & 1u)) >> 16);
}

// ---------- inline int64 edge_index detection ----------
__device__ __forceinline__ bool is_i64(const int* __restrict__ e) {
    int z = 0;
#pragma unroll
    for (int i = 0; i < 16; ++i) z |= e[2 * i + 1];
    return z == 0;
}

// ---------- FUSED: gemm1 (blocks < gemmBlocks) + hist_rank (rest) ----------
// Independent work co-scheduled in one launch (r14-proven, 70 us ~ max of both).
template <int OUT_DIM, int GST>
__global__ __launch_bounds__(256) void gemm1_hist_fused(
        const float* __restrict__ in, const float* __restrict__ Wl,
        const float* __restrict__ Wr, const float* __restrict__ bias,
        unsigned short* __restrict__ gout, float* __restrict__ sout,
        int n_nodes, int gemmBlocks,
        const int* __restrict__ eidx, int n_edges,
        int* __restrict__ deg, int* __restrict__ rank) {
    __shared__ unsigned int sWp[64][65];
    __shared__ float sB[OUT_DIM];
    __shared__ float sX[4][8][68];

    if ((int)blockIdx.x >= gemmBlocks) {
        const int half = (n_edges + 1) / 2;
        const int e = (blockIdx.x - gemmBlocks) * blockDim.x + threadIdx.x;
        if (e >= half) return;
        const bool i64 = is_i64(eidx);
        {
            int d = i64 ? eidx[2 * (n_edges + e)] : eidx[n_edges + e];
            rank[e] = atomicAdd(&deg[d], 1);
        }
        const int e2 = e + half;
        if (e2 < n_edges) {
            int d = i64 ? eidx[2 * (n_edges + e2)] : eidx[n_edges + e2];
            rank[e2] = atomicAdd(&deg[d], 1);
        }
        return;
    }

    for (int idx = threadIdx.x; idx < OUT_DIM * 64; idx += 256) {
        const int r = idx >> 6, c = idx & 63;
        sWp[c][r] = (unsigned int)f2bf(Wl[idx]) | ((unsigned int)f2bf(Wr[idx]) << 16);
    }
    if (threadIdx.x < OUT_DIM) sB[threadIdx.x] = bias[threadIdx.x];
    __syncthreads();

    const int g = threadIdx.x >> 6;
    const int j = threadIdx.x & 63;
    const bool jv = (j < OUT_DIM);
    const int jj = jv ? j : 0;
    const int blockBase = blockIdx.x * 128;

#pragma unroll 1
    for (int it = 0; it < 4; ++it) {
        const int nb = blockBase + it * 32 + g * 8;
        if (nb >= n_nodes) break;
#pragma unroll
        for (int n = 0; n < 8; ++n) {
            const int node = nb + n;
            sX[g][n][j] = (node < n_nodes) ? in[(size_t)node * 64 + j] : 0.0f;
        }
        float al[8], ar[8];
#pragma unroll
        for (int n = 0; n < 8; ++n) { al[n] = 0.0f; ar[n] = 0.0f; }

#pragma unroll 2
        for (int q = 0; q < 16; ++q) {
            const unsigned int w0 = sWp[4 * q + 0][jj];
            const unsigned int w1 = sWp[4 * q + 1][jj];
            const unsigned int w2 = sWp[4 * q + 2][jj];
            const unsigned int w3 = sWp[4 * q + 3][jj];
            const float4 x0 = *(const float4*)&sX[g][0][4 * q];
            const float4 x1 = *(const float4*)&sX[g][1][4 * q];
            const float4 x2 = *(const float4*)&sX[g][2][4 * q];
            const float4 x3 = *(const float4*)&sX[g][3][4 * q];
            const float4 x4 = *(const float4*)&sX[g][4][4 * q];
            const float4 x5 = *(const float4*)&sX[g][5][4 * q];
            const float4 x6 = *(const float4*)&sX[g][6][4 * q];
            const float4 x7 = *(const float4*)&sX[g][7][4 * q];
#define DG_STEP(WP, M)                                                         \
            {                                                                  \
                const float wl_ = __uint_as_float((WP) << 16);                 \
                const float wr_ = __uint_as_float((WP) & 0xFFFF0000u);         \
                al[0] = fmaf(x0.M, wl_, al[0]); ar[0] = fmaf(x0.M, wr_, ar[0]);\
                al[1] = fmaf(x1.M, wl_, al[1]); ar[1] = fmaf(x1.M, wr_, ar[1]);\
                al[2] = fmaf(x2.M, wl_, al[2]); ar[2] = fmaf(x2.M, wr_, ar[2]);\
                al[3] = fmaf(x3.M, wl_, al[3]); ar[3] = fmaf(x3.M, wr_, ar[3]);\
                al[4] = fmaf(x4.M, wl_, al[4]); ar[4] = fmaf(x4.M, wr_, ar[4]);\
                al[5] = fmaf(x5.M, wl_, al[5]); ar[5] = fmaf(x5.M, wr_, ar[5]);\
                al[6] = fmaf(x6.M, wl_, al[6]); ar[6] = fmaf(x6.M, wr_, ar[6]);\
                al[7] = fmaf(x7.M, wl_, al[7]); ar[7] = fmaf(x7.M, wr_, ar[7]);\
            }
            DG_STEP(w0, x)
            DG_STEP(w1, y)
            DG_STEP(w2, z)
            DG_STEP(w3, w)
#undef DG_STEP
        }

        const float bb = jv ? sB[jj] : 0.0f;
#pragma unroll
        for (int n = 0; n < 8; ++n) {
            const int node = nb + n;
            if (node < n_nodes) {
                if (jv) {
                    gout[(size_t)node * GST + j] = f2bf(al[n]);
                    sout[(size_t)node * OUT_DIM + j] = ar[n] + bb;
                } else if (j < GST) {
                    gout[(size_t)node * GST + j] = 0;
                }
            }
        }
    }
}

// ---------- standalone hist + rank (tierC/D path) ----------
__global__ void hist_rank_kernel(const int* __restrict__ eidx, int n_edges,
                                 int* __restrict__ deg, int* __restrict__ rank) {
    const int half = (n_edges + 1) / 2;
    const int e = blockIdx.x * blockDim.x + threadIdx.x;
    if (e >= half) return;
    const bool i64 = is_i64(eidx);
    {
        int d = i64 ? eidx[2 * (n_edges + e)] : eidx[n_edges + e];
        rank[e] = atomicAdd(&deg[d], 1);
    }
    const int e2 = e + half;
    if (e2 < n_edges) {
        int d = i64 ? eidx[2 * (n_edges + e2)] : eidx[n_edges + e2];
        rank[e2] = atomicAdd(&deg[d], 1);
    }
}

// ---------- atomic-free fill ----------
__global__ void fill_rank_kernel(const int* __restrict__ eidx, int n_edges,
                                 const int* __restrict__ off, const int* __restrict__ rank,
                                 int* __restrict__ csr) {
    const int half = (n_edges + 1) / 2;
    const int e = blockIdx.x * blockDim.x + threadIdx.x;
    if (e >= half) return;
    const bool i64 = is_i64(eidx);
    {
        int s, d;
        if (i64) { s = eidx[2 * e]; d = eidx[2 * (n_edges + e)]; }
        else     { s = eidx[e];     d = eidx[n_edges + e]; }
        __builtin_nontemporal_store(s, &csr[off[d] + rank[e]]);
    }
    const int e2 = e + half;
    if (e2 < n_edges) {
        int s, d;
        if (i64) { s = eidx[2 * e2]; d = eidx[2 * (n_edges + e2)]; }
        else     { s = eidx[e2];     d = eidx[n_edges + e2]; }
        __builtin_nontemporal_store(s, &csr[off[d] + rank[e2]]);
    }
}

// ---------- legacy atomic fill (tierC/D) ----------
__global__ void fill_kernel(const int* __restrict__ eidx, int n_edges,
                            int* __restrict__ cursor, int* __restrict__ csr) {
    int e = blockIdx.x * blockDim.x + threadIdx.x;
    if (e >= n_edges) return;
    const bool i64 = is_i64(eidx);
    int s, d;
    if (i64) { s = eidx[2 * e]; d = eidx[2 * (n_edges + e)]; }
    else     { s = eidx[e];     d = eidx[n_edges + e]; }
    int pos = atomicAdd(&cursor[d], 1);
    csr[pos] = s;
}

// ---------- 3-phase parallel exclusive scan ----------
#define TILE 1024
__global__ void scan_p1(const int* __restrict__ deg, int* __restrict__ bsum, int n) {
    __shared__ int red[256];
    const int t = threadIdx.x;
    const int base = blockIdx.x * TILE + t * 4;
    int s = 0;
#pragma unroll
    for (int k = 0; k < 4; ++k) { int i = base + k; if (i < n) s += deg[i]; }
    red[t] = s;
    __syncthreads();
    for (int d = 128; d > 0; d >>= 1) {
        if (t < d) red[t] += red[t + d];
        __syncthreads();
    }
    if (t == 0) bsum[blockIdx.x] = red[0];
}

__global__ void scan_p2(int* __restrict__ bsum, int* __restrict__ off, int nb, int n) {
    __shared__ int s[1024];
    const int t = threadIdx.x;
    s[t] = (t < nb) ? bsum[t] : 0;
    __syncthreads();
    for (int d = 1; d < 1024; d <<= 1) {
        int v = (t >= d) ? s[t - d] : 0;
        __syncthreads();
        s[t] += v;
        __syncthreads();
    }
    if (t < nb) bsum[t] = (t == 0) ? 0 : s[t - 1];
    if (t == 0) off[n] = s[nb - 1];
}

// wc != 0: also initialize cursor (tierC/D atomic-fill path). tierA skips it.
__global__ void scan_p3(const int* __restrict__ deg, const int* __restrict__ bsum,
                        int* __restrict__ off, int* __restrict__ cursor, int n, int wc) {
    __shared__ int red[256];
    const int t = threadIdx.x;
    const int base = blockIdx.x * TILE + t * 4;
    int v0 = 0, v1 = 0, v2 = 0, v3 = 0;
    if (base + 0 < n) v0 = deg[base + 0];
    if (base + 1 < n) v1 = deg[base + 1];
    if (base + 2 < n) v2 = deg[base + 2];
    if (base + 3 < n) v3 = deg[base + 3];
    const int mysum = v0 + v1 + v2 + v3;
    red[t] = mysum;
    __syncthreads();
    for (int d = 1; d < 256; d <<= 1) {
        int u = (t >= d) ? red[t - d] : 0;
        __syncthreads();
        red[t] += u;
        __syncthreads();
    }
    int run = bsum[blockIdx.x] + red[t] - mysum;
    if (wc) {
        if (base + 0 < n) { off[base + 0] = run; cursor[base + 0] = run; run += v0; }
        if (base + 1 < n) { off[base + 1] = run; cursor[base + 1] = run; run += v1; }
        if (base + 2 < n) { off[base + 2] = run; cursor[base + 2] = run; run += v2; }
        if (base + 3 < n) { off[base + 3] = run; cursor[base + 3] = run; run += v3; }
    } else {
        if (base + 0 < n) { off[base + 0] = run; run += v0; }
        if (base + 1 < n) { off[base + 1] = run; run += v1; }
        if (base + 2 < n) { off[base + 2] = run; run += v2; }
        if (base + 3 < n) { off[base + 3] = run; run += v3; }
    }
}

// ---------- pure bf16 gather: out = [relu]( gather_mean(gsrc) + sadd ) ----------
// Consecutive nodes share CSR boundaries: carry e1 -> e0 (halves off[] loads).
template <int SRC_STRIDE, int CGROUPS, int OUT_DIM, bool RELU>
__global__ __launch_bounds__(256) void gather_addmul_bf16(
        const unsigned short* __restrict__ gsrc,
        const float* __restrict__ sadd,
        const int* __restrict__ off, const int* __restrict__ csr,
        float* __restrict__ out, int n_nodes) {
    const int l = threadIdx.x & 63;
    const int wave = (int)((blockIdx.x * blockDim.x + threadIdx.x) >> 6);
    const int c = l & 15, r = l >> 4;
    const bool cact = (c < CGROUPS);
    const int n0 = wave * 8;
    if (n0 >= n_nodes) return;

    int e0 = off[n0];
    for (int n = n0; n < n0 + 8; ++n) {
        if (n >= n_nodes) return;
        const int e1 = off[n + 1];
        float4 a0 = {0.f,0.f,0.f,0.f}, a1 = a0, a2 = a0, a3 = a0;
        for (int i = e0; i < e1; i += 16) {
            const int i0 = i + r, i1 = i0 + 4, i2 = i0 + 8, i3 = i0 + 12;
            if (cact && i0 < e1) {
                const int s = csr[i0];
                const ushort4 u = *(const ushort4*)(gsrc + (size_t)s * SRC_STRIDE + 4 * c);
                a0.x += bf2f(u.x); a0.y += bf2f(u.y); a0.z += bf2f(u.z); a0.w += bf2f(u.w);
            }
            if (cact && i1 < e1) {
                const int s = csr[i1];
                const ushort4 u = *(const ushort4*)(gsrc + (size_t)s * SRC_STRIDE + 4 * c);
                a1.x += bf2f(u.x); a1.y += bf2f(u.y); a1.z += bf2f(u.z); a1.w += bf2f(u.w);
            }
            if (cact && i2 < e1) {
                const int s = csr[i2];
                const ushort4 u = *(const ushort4*)(gsrc + (size_t)s * SRC_STRIDE + 4 * c);
                a2.x += bf2f(u.x); a2.y += bf2f(u.y); a2.z += bf2f(u.z); a2.w += bf2f(u.w);
            }
            if (cact && i3 < e1) {
                const int s = csr[i3];
                const ushort4 u = *(const ushort4*)(gsrc + (size_t)s * SRC_STRIDE + 4 * c);
                a3.x += bf2f(u.x); a3.y += bf2f(u.y); a3.z += bf2f(u.z); a3.w += bf2f(u.w);
            }
        }
        float4 a;
        a.x = (a0.x + a1.x) + (a2.x + a3.x);
        a.y = (a0.y + a1.y) + (a2.y + a3.y);
        a.z = (a0.z + a1.z) + (a2.z + a3.z);
        a.w = (a0.w + a1.w) + (a2.w + a3.w);
        a.x += __shfl_xor(a.x, 16); a.y += __shfl_xor(a.y, 16);
        a.z += __shfl_xor(a.z, 16); a.w += __shfl_xor(a.w, 16);
        a.x += __shfl_xor(a.x, 32); a.y += __shfl_xor(a.y, 32);
        a.z += __shfl_xor(a.z, 32); a.w += __shfl_xor(a.w, 32);
        const int deg = e1 - e0;
        const float inv = (deg > 0) ? 1.0f / (float)deg : 0.0f;
        if (4 * l < OUT_DIM) {
            const float4 sv = *(const float4*)(sadd + (size_t)n * OUT_DIM + 4 * l);
            float4 o;
            o.x = fmaf(a.x, inv, sv.x);
            o.y = fmaf(a.y, inv, sv.y);
            o.z = fmaf(a.z, inv, sv.z);
            o.w = fmaf(a.w, inv, sv.w);
            if (RELU) {
                o.x = fmaxf(o.x, 0.f); o.y = fmaxf(o.y, 0.f);
                o.z = fmaxf(o.z, 0.f); o.w = fmaxf(o.w, 0.f);
            }
            *(float4*)(out + (size_t)n * OUT_DIM + 4 * l) = o;
        }
        e0 = e1;
    }
}

// ---------- dual GEMM v3 (standalone, layer 2) ----------
template <int OUT_DIM, int GST>
__global__ __launch_bounds__(256) void dual_gemm3(
        const float* __restrict__ in,
        const float* __restrict__ Wl, const float* __restrict__ Wr,
        const float* __restrict__ bias,
        unsigned short* __restrict__ gout,
        float* __restrict__ sout,
        int n_nodes) {
    __shared__ unsigned int sWp[64][65];
    __shared__ float sB[OUT_DIM];
    __shared__ float sX[4][8][68];

    for (int idx = threadIdx.x; idx < OUT_DIM * 64; idx += 256) {
        const int r = idx >> 6, c = idx & 63;
        sWp[c][r] = (unsigned int)f2bf(Wl[idx]) | ((unsigned int)f2bf(Wr[idx]) << 16);
    }
    if (threadIdx.x < OUT_DIM) sB[threadIdx.x] = bias[threadIdx.x];
    __syncthreads();

    const int g = threadIdx.x >> 6;
    const int j = threadIdx.x & 63;
    const bool jv = (j < OUT_DIM);
    const int jj = jv ? j : 0;
    const int blockBase = blockIdx.x * 128;

#pragma unroll 1
    for (int it = 0; it < 4; ++it) {
        const int nb = blockBase + it * 32 + g * 8;
        if (nb >= n_nodes) break;
#pragma unroll
        for (int n = 0; n < 8; ++n) {
            const int node = nb + n;
            sX[g][n][j] = (node < n_nodes) ? in[(size_t)node * 64 + j] : 0.0f;
        }
        float al[8], ar[8];
#pragma unroll
        for (int n = 0; n < 8; ++n) { al[n] = 0.0f; ar[n] = 0.0f; }

#pragma unroll 2
        for (int q = 0; q < 16; ++q) {
            const unsigned int w0 = sWp[4 * q + 0][jj];
            const unsigned int w1 = sWp[4 * q + 1][jj];
            const unsigned int w2 = sWp[4 * q + 2][jj];
            const unsigned int w3 = sWp[4 * q + 3][jj];
            const float4 x0 = *(const float4*)&sX[g][0][4 * q];
            const float4 x1 = *(const float4*)&sX[g][1][4 * q];
            const float4 x2 = *(const float4*)&sX[g][2][4 * q];
            const float4 x3 = *(const float4*)&sX[g][3][4 * q];
            const float4 x4 = *(const float4*)&sX[g][4][4 * q];
            const float4 x5 = *(const float4*)&sX[g][5][4 * q];
            const float4 x6 = *(const float4*)&sX[g][6][4 * q];
            const float4 x7 = *(const float4*)&sX[g][7][4 * q];
#define DG_STEP(WP, M)                                                         \
            {                                                                  \
                const float wl_ = __uint_as_float((WP) << 16);                 \
                const float wr_ = __uint_as_float((WP) & 0xFFFF0000u);         \
                al[0] = fmaf(x0.M, wl_, al[0]); ar[0] = fmaf(x0.M, wr_, ar[0]);\
                al[1] = fmaf(x1.M, wl_, al[1]); ar[1] = fmaf(x1.M, wr_, ar[1]);\
                al[2] = fmaf(x2.M, wl_, al[2]); ar[2] = fmaf(x2.M, wr_, ar[2]);\
                al[3] = fmaf(x3.M, wl_, al[3]); ar[3] = fmaf(x3.M, wr_, ar[3]);\
                al[4] = fmaf(x4.M, wl_, al[4]); ar[4] = fmaf(x4.M, wr_, ar[4]);\
                al[5] = fmaf(x5.M, wl_, al[5]); ar[5] = fmaf(x5.M, wr_, ar[5]);\
                al[6] = fmaf(x6.M, wl_, al[6]); ar[6] = fmaf(x6.M, wr_, ar[6]);\
                al[7] = fmaf(x7.M, wl_, al[7]); ar[7] = fmaf(x7.M, wr_, ar[7]);\
            }
            DG_STEP(w0, x)
            DG_STEP(w1, y)
            DG_STEP(w2, z)
            DG_STEP(w3, w)
#undef DG_STEP
        }

        const float bb = jv ? sB[jj] : 0.0f;
#pragma unroll
        for (int n = 0; n < 8; ++n) {
            const int node = nb + n;
            if (node < n_nodes) {
                if (jv) {
                    gout[(size_t)node * GST + j] = f2bf(al[n]);
                    sout[(size_t)node * OUT_DIM + j] = ar[n] + bb;
                } else if (j < GST) {
                    gout[(size_t)node * GST + j] = 0;
                }
            }
        }
    }
}

// ---------- tierC: fused layer, f4 gather + in-kernel dense (f32 only) ----------
#define NPB 32
template <int OUT_DIM, bool RELU>
__global__ __launch_bounds__(512, 8) void fused_layer_f4(
        const float* __restrict__ feat,
        const int* __restrict__ off, const int* __restrict__ csr,
        const float* __restrict__ Wl, const float* __restrict__ Wr,
        const float* __restrict__ bias,
        float* __restrict__ out, int n_nodes) {
    __shared__ float sWl[OUT_DIM][65];
    __shared__ float sWr[OUT_DIM][65];
    __shared__ float sB[OUT_DIM];
    __shared__ float sA[8][64];
    __shared__ float sX[8][64];

    for (int idx = threadIdx.x; idx < OUT_DIM * 64; idx += 512) {
        sWl[idx >> 6][idx & 63] = Wl[idx];
        sWr[idx >> 6][idx & 63] = Wr[idx];
    }
    if (threadIdx.x < OUT_DIM) sB[threadIdx.x] = bias[threadIdx.x];
    __syncthreads();

    const int g = threadIdx.x >> 6;
    const int l = threadIdx.x & 63;
    const int c = l & 15, r = l >> 4;
    const int base = blockIdx.x * NPB;

#pragma unroll 1
    for (int it = 0; it < NPB / 8; ++it) {
        const int node = base + it * 8 + g;
        if (node >= n_nodes) break;
        const int e0 = off[node], e1 = off[node + 1];
        const float selfv = feat[(size_t)node * 64 + l];
        float4 a0 = {0.f,0.f,0.f,0.f}, a1 = a0, a2 = a0, a3 = a0;
        for (int i = e0; i < e1; i += 16) {
            const int i0 = i + r, i1 = i0 + 4, i2 = i0 + 8, i3 = i0 + 12;
            if (i0 < e1) { const int s = csr[i0];
                const float4 v = *(const float4*)(feat + (size_t)s * 64 + 4 * c);
                a0.x += v.x; a0.y += v.y; a0.z += v.z; a0.w += v.w; }
            if (i1 < e1) { const int s = csr[i1];
                const float4 v = *(const float4*)(feat + (size_t)s * 64 + 4 * c);
                a1.x += v.x; a1.y += v.y; a1.z += v.z; a1.w += v.w; }
            if (i2 < e1) { const int s = csr[i2];
                const float4 v = *(const float4*)(feat + (size_t)s * 64 + 4 * c);
                a2.x += v.x; a2.y += v.y; a2.z += v.z; a2.w += v.w; }
            if (i3 < e1) { const int s = csr[i3];
                const float4 v = *(const float4*)(feat + (size_t)s * 64 + 4 * c);
                a3.x += v.x; a3.y += v.y; a3.z += v.z; a3.w += v.w; }
        }
        float4 a;
        a.x = (a0.x + a1.x) + (a2.x + a3.x);
        a.y = (a0.y + a1.y) + (a2.y + a3.y);
        a.z = (a0.z + a1.z) + (a2.z + a3.z);
        a.w = (a0.w + a1.w) + (a2.w + a3.w);
        a.x += __shfl_xor(a.x, 16); a.y += __shfl_xor(a.y, 16);
        a.z += __shfl_xor(a.z, 16); a.w += __shfl_xor(a.w, 16);
        a.x += __shfl_xor(a.x, 32); a.y += __shfl_xor(a.y, 32);
        a.z += __shfl_xor(a.z, 32); a.w += __shfl_xor(a.w, 32);
        const int deg = e1 - e0;
        const float inv = (deg > 0) ? 1.0f / (float)deg : 0.0f;
        if (l < 16) {
            float4 s4;
            s4.x = a.x * inv; s4.y = a.y * inv; s4.z = a.z * inv; s4.w = a.w * inv;
            *(float4*)&sA[g][4 * l] = s4;
        }
        sX[g][l] = selfv;
        if (l < OUT_DIM) {
            float acc = sB[l];
#pragma unroll
            for (int k = 0; k < 64; ++k) {
                acc = fmaf(sA[g][k], sWl[l][k], acc);
                acc = fmaf(sX[g][k], sWr[l][k], acc);
            }
            if (RELU) acc = fmaxf(acc, 0.0f);
            out[(size_t)node * OUT_DIM + l] = acc;
        }
    }
}

// ---------- tierD: legacy shfl-gather fused layer (bf16-capable) ----------
template <int OUT_DIM, bool RELU, bool FEAT_BF16, bool OUT_BF16>
__global__ __launch_bounds__(512, 8) void fused_layer(
        const void* __restrict__ feat,
        const int* __restrict__ off, const int* __restrict__ csr,
        const float* __restrict__ Wl, const float* __restrict__ Wr,
        const float* __restrict__ bias,
        void* __restrict__ out, int n_nodes) {
    __shared__ float sWl[OUT_DIM][65];
    __shared__ float sWr[OUT_DIM][65];
    __shared__ float sB[OUT_DIM];
    __shared__ float sA[8][64];
    __shared__ float sX[8][64];

    for (int idx = threadIdx.x; idx < OUT_DIM * 64; idx += 512) {
        sWl[idx >> 6][idx & 63] = Wl[idx];
        sWr[idx >> 6][idx & 63] = Wr[idx];
    }
    if (threadIdx.x < OUT_DIM) sB[threadIdx.x] = bias[threadIdx.x];
    __syncthreads();

    const int g = threadIdx.x >> 6;
    const int j = threadIdx.x & 63;
    const int base = blockIdx.x * NPB;

#pragma unroll 1
    for (int it = 0; it < NPB / 8; ++it) {
        const int node = base + it * 8 + g;
        if (node >= n_nodes) break;
        const int e0 = off[node], e1 = off[node + 1];
        float a0 = 0.f, a1 = 0.f, a2 = 0.f, a3 = 0.f;
        int i = e0;
        while (i < e1) {
            const int cnt = ((e1 - i) < 64) ? (e1 - i) : 64;
            const int eid = (j < cnt) ? csr[i + j] : 0;
            int t = 0;
            for (; t + 3 < cnt; t += 4) {
                const int s0 = __shfl(eid, t);
                const int s1 = __shfl(eid, t + 1);
                const int s2 = __shfl(eid, t + 2);
                const int s3 = __shfl(eid, t + 3);
                if (FEAT_BF16) {
                    a0 += bf2f(((const unsigned short*)feat)[(size_t)s0 * 64 + j]);
                    a1 += bf2f(((const unsigned short*)feat)[(size_t)s1 * 64 + j]);
                    a2 += bf2f(((const unsigned short*)feat)[(size_t)s2 * 64 + j]);
                    a3 += bf2f(((const unsigned short*)feat)[(size_t)s3 * 64 + j]);
                } else {
                    a0 += ((const float*)feat)[(size_t)s0 * 64 + j];
                    a1 += ((const float*)feat)[(size_t)s1 * 64 + j];
                    a2 += ((const float*)feat)[(size_t)s2 * 64 + j];
                    a3 += ((const float*)feat)[(size_t)s3 * 64 + j];
                }
            }
            for (; t < cnt; ++t) {
                const int s0 = __shfl(eid, t);
                a0 += FEAT_BF16 ? bf2f(((const unsigned short*)feat)[(size_t)s0 * 64 + j])
                                : ((const float*)feat)[(size_t)s0 * 64 + j];
            }
            i += cnt;
        }
        const int deg = e1 - e0;
        const float inv = (deg > 0) ? 1.0f / (float)deg : 0.0f;
        sA[g][j] = ((a0 + a1) + (a2 + a3)) * inv;
        sX[g][j] = FEAT_BF16 ? bf2f(((const unsigned short*)feat)[(size_t)node * 64 + j])
                             : ((const float*)feat)[(size_t)node * 64 + j];
        if (j < OUT_DIM) {
            float acc = sB[j];
#pragma unroll
            for (int k = 0; k < 64; ++k) {
                acc = fmaf(sA[g][k], sWl[j][k], acc);
                acc = fmaf(sX[g][k], sWr[j][k], acc);
            }
            if (RELU) acc = fmaxf(acc, 0.0f);
            if (OUT_BF16)
                ((unsigned short*)out)[(size_t)node * OUT_DIM + j] = f2bf(acc);
            else
                ((float*)out)[(size_t)node * OUT_DIM + j] = acc;
        }
    }
}

extern "C" void kernel_launch(void* const* d_in, const int* in_sizes, int n_in,
                              void* d_out, int out_size, void* d_ws, size_t ws_size,
                              hipStream_t stream) {
    const float* x   = (const float*)d_in[0];
    const int*   ei  = (const int*)d_in[1];
    const float* W1l = (const float*)d_in[2];
    const float* W1r = (const float*)d_in[3];
    const float* b1  = (const float*)d_in[4];
    const float* W2l = (const float*)d_in[5];
    const float* W2r = (const float*)d_in[6];
    const float* b2  = (const float*)d_in[7];
    float* out = (float*)d_out;

    const int n_nodes = in_sizes[0] / 64;
    const int n_edges = in_sizes[1] / 2;

    // ---- workspace layout ----
    const size_t off_b  = (size_t)(n_nodes + 1) * sizeof(int);
    const size_t cur_b  = (size_t)n_nodes * sizeof(int);
    const size_t csr_b  = (size_t)n_edges * sizeof(int);
    const size_t rank_b = (size_t)n_edges * sizeof(int);
    const size_t bsum_b = 1024 * sizeof(int);
    const size_t g1_b   = (size_t)n_nodes * 64 * sizeof(unsigned short);
    const size_t s1_b   = (size_t)n_nodes * 64 * sizeof(float);
    const size_t g2_b   = (size_t)n_nodes * 48 * sizeof(unsigned short);
    const size_t h_b    = (size_t)n_nodes * 64 * sizeof(float);
    const size_t reg1_b = g1_b + s1_b;

    char* p = (char*)d_ws;
    int* off    = (int*)p;  p += off_b;
    int* cursor = (int*)p;  p += cur_b;
    int* csr    = (int*)p;  p += csr_b;
    int* rank   = (int*)p;  p += rank_b;
    int* bsum   = (int*)p;  p += bsum_b;
    size_t used = ((size_t)(p - (char*)d_ws) + 255) / 256 * 256;
    p = (char*)d_ws + used;

    const bool tierA = ws_size >= used + reg1_b + h_b;   // g2|s2 overlay g1|s1
    const bool tierC = ws_size >= used + h_b;

    unsigned short* g1 = (unsigned short*)p;
    float*          s1 = (float*)(p + g1_b);
    unsigned short* g2 = (unsigned short*)p;     // overlays g1 (dead by then)
    float*          s2 = (float*)(p + g2_b);

    hipMemsetAsync(cursor, 0, cur_b, stream);

    const int half = (n_edges + 1) / 2;
    const int hblocks = (half + 255) / 256;
    const int gemmBlocks   = (n_nodes + 127) / 128;
    const int gatherBlocks = (n_nodes + 31) / 32;
    const int fusedBlocks  = (n_nodes + NPB - 1) / NPB;
    const int nb = (n_nodes + TILE - 1) / TILE;
    const int eblocks = (n_edges + 255) / 256;

    if (tierA) {
        // gemm1 and hist are independent -> one co-scheduled launch
        gemm1_hist_fused<64, 64><<<gemmBlocks + hblocks, 256, 0, stream>>>(
            x, W1l, W1r, b1, g1, s1, n_nodes, gemmBlocks,
            ei, n_edges, cursor, rank);
        scan_p1<<<nb, 256, 0, stream>>>(cursor, bsum, n_nodes);
        scan_p2<<<1, 1024, 0, stream>>>(bsum, off, nb, n_nodes);
        scan_p3<<<nb, 256, 0, stream>>>(cursor, bsum, off, cursor, n_nodes, 0);
        fill_rank_kernel<<<hblocks, 256, 0, stream>>>(ei, n_edges, off, rank, csr);

        float* h = s1 + (size_t)n_nodes * 64;    // unused tail? no -- reuse below
        (void)h;
        // h buffer: place after reg1 region (tierA guarantees reg1 + h fits)
        float* hbuf = (float*)(p + reg1_b);
        gather_addmul_bf16<64, 16, 64, true><<<gatherBlocks, 256, 0, stream>>>(
            g1, s1, off, csr, hbuf, n_nodes);
        dual_gemm3<40, 48><<<gemmBlocks, 256, 0, stream>>>(
            hbuf, W2l, W2r, b2, g2, s2, n_nodes);
        gather_addmul_bf16<48, 10, 40, false><<<gatherBlocks, 256, 0, stream>>>(
            g2, s2, off, csr, out, n_nodes);
    } else {
        hist_rank_kernel<<<hblocks, 256, 0, stream>>>(ei, n_edges, cursor, rank);
        scan_p1<<<nb, 256, 0, stream>>>(cursor, bsum, n_nodes);
        scan_p2<<<1, 1024, 0, stream>>>(bsum, off, nb, n_nodes);
        scan_p3<<<nb, 256, 0, stream>>>(cursor, bsum, off, cursor, n_nodes, 1);
        fill_kernel<<<eblocks, 256, 0, stream>>>(ei, n_edges, cursor, csr);

        if (tierC) {
            float* hh = (float*)p;
            fused_layer_f4<64, true><<<fusedBlocks, 512, 0, stream>>>(
                x, off, csr, W1l, W1r, b1, hh, n_nodes);
            fused_layer_f4<40, false><<<fusedBlocks, 512, 0, stream>>>(
                hh, off, csr, W2l, W2r, b2, out, n_nodes);
        } else {
            void* hh = (void*)p;
            fused_layer<64, true, false, true><<<fusedBlocks, 512, 0, stream>>>(
                x, off, csr, W1l, W1r, b1, hh, n_nodes);
            fused_layer<40, false, true, false><<<fusedBlocks, 512, 0, stream>>>(
                hh, off, csr, W2l, W2r, b2, out, n_nodes);
        }
    }
}